// Round 2
// baseline (686.400 us; speedup 1.0000x reference)
//
#include <hip/hip_runtime.h>
#include <math.h>

#define NN 8192
#define FF 64
#define ALPHA 0.2f
#define ECAP 512   // k_e per-wave nz-list capacity (row mean 164, max ~230, +4 pad)
#define WCAP 256   // k_att per-wave segment capacity (mean 41, max ~90, +4 pad)
#define ROWS_PER_BLK 4   // k_att: rows per block (amortizes the e-max recompute)

typedef float vf4 __attribute__((ext_vector_type(4)));  // clang vector: ok for nontemporal builtins

// popcount of ballot mask below this lane: v_mbcnt_lo + v_mbcnt_hi (2 VALU)
__device__ __forceinline__ unsigned mbcnt64(unsigned long long m) {
    return __builtin_amdgcn_mbcnt_hi((unsigned)(m >> 32),
           __builtin_amdgcn_mbcnt_lo((unsigned)m, 0u));
}

// ---------------- Kernel 1: e[i] ----------------
// Algebraic fusion: (sgn(node_adj) @ (h @ W)) == ((sgn(node_adj) @ h) @ W),
// so gather h rows directly (u = signed sum, 64-dim), then apply W per row:
// a_input = |u @ W|, e = leakyrelu(a_input . a).  k_hatt eliminated.
__global__ __launch_bounds__(256) void k_e(const float* __restrict__ node_adj,
                                           const float* __restrict__ h,
                                           const float* __restrict__ W,
                                           const float* __restrict__ a,
                                           float* __restrict__ e) {
    __shared__ int lists[4][ECAP];
    __shared__ vf4 u_s[4][16];
    int t = threadIdx.x, w = t >> 6, lane = t & 63;
    int row = blockIdx.x * 4 + w;
    const vf4* rp = (const vf4*)(node_adj + (size_t)row * NN);
    int cnt = 0;
#pragma unroll 4
    for (int it = 0; it < 32; ++it) {
        int idx = it * 64 + lane;
        vf4 v = __builtin_nontemporal_load(rp + idx);
        int j0 = idx * 4;
        { bool nz = v.x != 0.f; unsigned long long m = __ballot(nz);
          if (nz) lists[w][cnt + mbcnt64(m)] = (v.x > 0.f) ? (j0 + 1) : -(j0 + 1);
          cnt += __popcll(m); }
        { bool nz = v.y != 0.f; unsigned long long m = __ballot(nz);
          if (nz) lists[w][cnt + mbcnt64(m)] = (v.y > 0.f) ? (j0 + 2) : -(j0 + 2);
          cnt += __popcll(m); }
        { bool nz = v.z != 0.f; unsigned long long m = __ballot(nz);
          if (nz) lists[w][cnt + mbcnt64(m)] = (v.z > 0.f) ? (j0 + 3) : -(j0 + 3);
          cnt += __popcll(m); }
        { bool nz = v.w != 0.f; unsigned long long m = __ballot(nz);
          if (nz) lists[w][cnt + mbcnt64(m)] = (v.w > 0.f) ? (j0 + 4) : -(j0 + 4);
          cnt += __popcll(m); }
    }
    // pad to multiple of 4 with sentinel 0 (contribution forced to 0 below)
    if (lane < 4) lists[w][cnt + lane] = 0;
    // no __syncthreads(): lists/u_s are strictly per-wave; same-wave LDS
    // write->read ordering is handled by in-order DS pipe + lgkmcnt waits.

    int g = lane >> 4, fl = lane & 15;     // group = gathered row, fl = feature quad
    const vf4* Hp = (const vf4*)h;
    vf4 acc = {0.f, 0.f, 0.f, 0.f};
    int cnt4 = (cnt + 3) & ~3;
#pragma unroll 2
    for (int k = 0; k < cnt4; k += 4) {
        int code = lists[w][k + g];        // 16-lane broadcast, 4 consecutive words
        float s = (code < 0) ? -1.f : (code > 0 ? 1.f : 0.f);
        int aj = (code < 0) ? -code : code;
        int j = (aj > 0) ? aj - 1 : 0;
        vf4 hv = Hp[(size_t)j * 16 + fl];  // 256B contiguous per 16-lane group
        acc.x += s * hv.x; acc.y += s * hv.y; acc.z += s * hv.z; acc.w += s * hv.w;
    }
    // cross-group reduce: groups 0..3 hold partials of the same 64 features
    acc.x += __shfl_xor(acc.x, 16, 64); acc.y += __shfl_xor(acc.y, 16, 64);
    acc.z += __shfl_xor(acc.z, 16, 64); acc.w += __shfl_xor(acc.w, 16, 64);
    acc.x += __shfl_xor(acc.x, 32, 64); acc.y += __shfl_xor(acc.y, 32, 64);
    acc.z += __shfl_xor(acc.z, 32, 64); acc.w += __shfl_xor(acc.w, 32, 64);

    // broadcast u (64 features) to the wave, then apply W: lane = output feature
    if (g == 0) u_s[w][fl] = acc;
    const float* us = (const float*)u_s[w];
    float s = 0.f;
#pragma unroll 8
    for (int k = 0; k < 64; ++k)
        s += us[k] * W[k * 64 + lane];     // us[k]: LDS broadcast; W: coalesced, L1-hot
    float v = fabsf(s) * a[lane];
#pragma unroll
    for (int off = 32; off; off >>= 1) v += __shfl_down(v, off, 64);
    if (lane == 0) e[row] = (v > 0.f) ? v : ALPHA * v;
}

// ---------------- Kernel 2: attention rows + h_prime (k_prep folded in) ----------------
// Per block: recompute m = max(e) once (32 KB, L2-resident, ~2 us aggregate at
// 2048 blocks), then process ROWS_PER_BLK rows.  E[j] = exp(e[j]-m) computed
// inline on the transcendental pipe — the E array and its launch are gone.
__global__ __launch_bounds__(256) void k_att(const float* __restrict__ edge_adj,
                                             const float* __restrict__ e_vec,
                                             const float* __restrict__ h,
                                             float* __restrict__ att_out,
                                             float* __restrict__ hprime) {
    __shared__ int2 seg[4][WCAP];
    __shared__ vf4  red4[64];
    __shared__ float r4z[4];
    __shared__ int   cnts[4];
    __shared__ float mred[256];
    int t = threadIdx.x, w = t >> 6, lane = t & 63;

    // ---- block-wide max over e[0..NN) ----
    const vf4* ep4 = (const vf4*)e_vec;
    float lm = -3.0e38f;
    for (int k = t; k < NN / 4; k += 256) {
        vf4 v = ep4[k];
        lm = fmaxf(lm, fmaxf(fmaxf(v.x, v.y), fmaxf(v.z, v.w)));
    }
    mred[t] = lm; __syncthreads();
    for (int s = 128; s; s >>= 1) { if (t < s) mred[t] = fmaxf(mred[t], mred[t + s]); __syncthreads(); }
    float m = mred[0];

    for (int r = 0; r < ROWS_PER_BLK; ++r) {
        int row = blockIdx.x * ROWS_PER_BLK + r;
        const vf4* rp = (const vf4*)(edge_adj + (size_t)row * NN);
        vf4 o[8];
        float zloc = 0.f;
        int cnt = 0;
#pragma unroll
        for (int it = 0; it < 8; ++it) {
            int idx = it * 256 + t;
            vf4 v  = __builtin_nontemporal_load(rp + idx);
            vf4 ev = ep4[idx];
            float Ex = __expf(ev.x - m), Ey = __expf(ev.y - m);
            float Ez = __expf(ev.z - m), Ew = __expf(ev.w - m);
            int j0 = idx * 4;
            { bool nz = v.x != 0.f; unsigned long long mm = __ballot(nz);
              float ox = nz ? Ex : 0.f;
              if (nz) seg[w][cnt + mbcnt64(mm)] = make_int2(j0,     __float_as_int(v.x * Ex));
              cnt += __popcll(mm); zloc += ox; o[it].x = ox; }
            { bool nz = v.y != 0.f; unsigned long long mm = __ballot(nz);
              float oy = nz ? Ey : 0.f;
              if (nz) seg[w][cnt + mbcnt64(mm)] = make_int2(j0 + 1, __float_as_int(v.y * Ey));
              cnt += __popcll(mm); zloc += oy; o[it].y = oy; }
            { bool nz = v.z != 0.f; unsigned long long mm = __ballot(nz);
              float oz = nz ? Ez : 0.f;
              if (nz) seg[w][cnt + mbcnt64(mm)] = make_int2(j0 + 2, __float_as_int(v.z * Ez));
              cnt += __popcll(mm); zloc += oz; o[it].z = oz; }
            { bool nz = v.w != 0.f; unsigned long long mm = __ballot(nz);
              float ow = nz ? Ew : 0.f;
              if (nz) seg[w][cnt + mbcnt64(mm)] = make_int2(j0 + 3, __float_as_int(v.w * Ew));
              cnt += __popcll(mm); zloc += ow; o[it].w = ow; }
        }
        if (lane == 0) cnts[w] = cnt;
#pragma unroll
        for (int off = 32; off; off >>= 1) zloc += __shfl_down(zloc, off, 64);
        if (lane == 0) r4z[w] = zloc;
        if (lane < 4) seg[w][cnt + lane] = make_int2(0, 0);   // sentinel pad (v=0)
        __syncthreads();
        float Z = r4z[0] + r4z[1] + r4z[2] + r4z[3];
        int tot = cnts[0] + cnts[1] + cnts[2] + cnts[3];
        float invZ = (tot > 0) ? 1.f / Z : 0.f;

        // ---- h_prime gather: 4x16 lane groups, vf4 loads of h rows ----
        int g = lane >> 4, fl = lane & 15;
        const vf4* Hp = (const vf4*)h;
        vf4 acc = {0.f, 0.f, 0.f, 0.f};
        int cnt4 = (cnt + 3) & ~3;
#pragma unroll 2
        for (int k = 0; k < cnt4; k += 4) {
            int2 sv = seg[w][k + g];           // single ds_read_b64, 16-lane broadcast
            float vv = __int_as_float(sv.y);
            vf4 hv = Hp[(size_t)sv.x * 16 + fl];
            acc.x += vv * hv.x; acc.y += vv * hv.y; acc.z += vv * hv.z; acc.w += vv * hv.w;
        }
        acc.x += __shfl_xor(acc.x, 16, 64); acc.y += __shfl_xor(acc.y, 16, 64);
        acc.z += __shfl_xor(acc.z, 16, 64); acc.w += __shfl_xor(acc.w, 16, 64);
        acc.x += __shfl_xor(acc.x, 32, 64); acc.y += __shfl_xor(acc.y, 32, 64);
        acc.z += __shfl_xor(acc.z, 32, 64); acc.w += __shfl_xor(acc.w, 32, 64);
        if (lane < 16) red4[w * 16 + fl] = acc;   // wave w's 64 features at red[w*64+f]
        __syncthreads();
        const float* red = (const float*)red4;
        if (t < 64)
            hprime[(size_t)row * FF + t] = (red[t] + red[t + 64] + red[t + 128] + red[t + 192]) * invZ;

        // ---- dense coalesced write ----
        vf4* ap = (vf4*)(att_out + (size_t)row * NN);
        float unif = 1.0f / NN;
#pragma unroll
        for (int it = 0; it < 8; ++it) {
            int idx = it * 256 + t;
            vf4 ov = o[it];
            ov.x *= invZ; ov.y *= invZ; ov.z *= invZ; ov.w *= invZ;
            if (tot == 0) { ov.x = unif; ov.y = unif; ov.z = unif; ov.w = unif; }
            __builtin_nontemporal_store(ov, ap + idx);
        }
        // Cross-iteration LDS safety: any wave's next-iteration writes to
        // seg/cnts/r4z happen only after it passed this iteration's second
        // barrier, which implies every wave's reads of those completed.
    }
}

extern "C" void kernel_launch(void* const* d_in, const int* in_sizes, int n_in,
                              void* d_out, int out_size, void* d_ws, size_t ws_size,
                              hipStream_t stream) {
    const float* h        = (const float*)d_in[0];
    const float* node_adj = (const float*)d_in[1];
    const float* edge_adj = (const float*)d_in[2];
    const float* W_att    = (const float*)d_in[3];
    const float* a        = (const float*)d_in[4];

    float* out    = (float*)d_out;
    float* hprime = out;                               // [8192, 64]
    float* att    = out + (size_t)NN * FF;             // [8192, 8192]

    float* e_vec = (float*)d_ws;                       // [8192]

    k_e<<<NN / 4, 256, 0, stream>>>(node_adj, h, W_att, a, e_vec);
    k_att<<<NN / ROWS_PER_BLK, 256, 0, stream>>>(edge_adj, e_vec, h, att, hprime);
}

// Round 3
// 607.057 us; speedup vs baseline: 1.1307x; 1.1307x over previous
//
#include <hip/hip_runtime.h>
#include <math.h>

#define NN 8192
#define FF 64
#define ALPHA 0.2f
#define ECAP 512   // k_e per-wave nz-list capacity (row mean 164, max ~230, +4 pad)
#define WCAP 256   // k_att per-wave segment capacity (mean 41, max ~90, +4 pad)

typedef float vf4 __attribute__((ext_vector_type(4)));  // clang vector: ok for nontemporal builtins

// popcount of ballot mask below this lane: v_mbcnt_lo + v_mbcnt_hi (2 VALU)
__device__ __forceinline__ unsigned mbcnt64(unsigned long long m) {
    return __builtin_amdgcn_mbcnt_hi((unsigned)(m >> 32),
           __builtin_amdgcn_mbcnt_lo((unsigned)m, 0u));
}

// ---------------- Kernel 1: e[i] ----------------
// Algebraic fusion: (sgn(node_adj) @ (h @ W)) == ((sgn(node_adj) @ h) @ W),
// so gather h rows directly (u = signed sum, 64-dim), then apply W per row:
// a_input = |u @ W|, e = leakyrelu(a_input . a).  k_hatt eliminated.
// (R2 measured this fusion as non-regressing; the R2 regression was k_att's
// ROWS_PER_BLK=4 grid shrink, reverted below.)
__global__ __launch_bounds__(256) void k_e(const float* __restrict__ node_adj,
                                           const float* __restrict__ h,
                                           const float* __restrict__ W,
                                           const float* __restrict__ a,
                                           float* __restrict__ e) {
    __shared__ int lists[4][ECAP];
    __shared__ vf4 u_s[4][16];
    int t = threadIdx.x, w = t >> 6, lane = t & 63;
    int row = blockIdx.x * 4 + w;
    const vf4* rp = (const vf4*)(node_adj + (size_t)row * NN);
    int cnt = 0;
#pragma unroll 4
    for (int it = 0; it < 32; ++it) {
        int idx = it * 64 + lane;
        vf4 v = __builtin_nontemporal_load(rp + idx);
        int j0 = idx * 4;
        { bool nz = v.x != 0.f; unsigned long long m = __ballot(nz);
          if (nz) lists[w][cnt + mbcnt64(m)] = (v.x > 0.f) ? (j0 + 1) : -(j0 + 1);
          cnt += __popcll(m); }
        { bool nz = v.y != 0.f; unsigned long long m = __ballot(nz);
          if (nz) lists[w][cnt + mbcnt64(m)] = (v.y > 0.f) ? (j0 + 2) : -(j0 + 2);
          cnt += __popcll(m); }
        { bool nz = v.z != 0.f; unsigned long long m = __ballot(nz);
          if (nz) lists[w][cnt + mbcnt64(m)] = (v.z > 0.f) ? (j0 + 3) : -(j0 + 3);
          cnt += __popcll(m); }
        { bool nz = v.w != 0.f; unsigned long long m = __ballot(nz);
          if (nz) lists[w][cnt + mbcnt64(m)] = (v.w > 0.f) ? (j0 + 4) : -(j0 + 4);
          cnt += __popcll(m); }
    }
    // pad to multiple of 4 with sentinel 0 (contribution forced to 0 below)
    if (lane < 4) lists[w][cnt + lane] = 0;
    // no __syncthreads(): lists/u_s are strictly per-wave; same-wave LDS
    // write->read ordering is handled by in-order DS pipe + lgkmcnt waits.

    int g = lane >> 4, fl = lane & 15;     // group = gathered row, fl = feature quad
    const vf4* Hp = (const vf4*)h;
    vf4 acc = {0.f, 0.f, 0.f, 0.f};
    int cnt4 = (cnt + 3) & ~3;
#pragma unroll 2
    for (int k = 0; k < cnt4; k += 4) {
        int code = lists[w][k + g];        // 16-lane broadcast, 4 consecutive words
        float s = (code < 0) ? -1.f : (code > 0 ? 1.f : 0.f);
        int aj = (code < 0) ? -code : code;
        int j = (aj > 0) ? aj - 1 : 0;
        vf4 hv = Hp[(size_t)j * 16 + fl];  // 256B contiguous per 16-lane group
        acc.x += s * hv.x; acc.y += s * hv.y; acc.z += s * hv.z; acc.w += s * hv.w;
    }
    // cross-group reduce: groups 0..3 hold partials of the same 64 features
    acc.x += __shfl_xor(acc.x, 16, 64); acc.y += __shfl_xor(acc.y, 16, 64);
    acc.z += __shfl_xor(acc.z, 16, 64); acc.w += __shfl_xor(acc.w, 16, 64);
    acc.x += __shfl_xor(acc.x, 32, 64); acc.y += __shfl_xor(acc.y, 32, 64);
    acc.z += __shfl_xor(acc.z, 32, 64); acc.w += __shfl_xor(acc.w, 32, 64);

    // broadcast u (64 features) to the wave, then apply W: lane = output feature
    if (g == 0) u_s[w][fl] = acc;
    const float* us = (const float*)u_s[w];
    float s = 0.f;
#pragma unroll 8
    for (int k = 0; k < 64; ++k)
        s += us[k] * W[k * 64 + lane];     // us[k]: LDS broadcast; W: coalesced, L1-hot
    float v = fabsf(s) * a[lane];
#pragma unroll
    for (int off = 32; off; off >>= 1) v += __shfl_down(v, off, 64);
    if (lane == 0) e[row] = (v > 0.f) ? v : ALPHA * v;
}

// ---------------- Kernel 2: E[j] = exp(e[j] - max(e)) ----------------
__global__ __launch_bounds__(256) void k_prep(const float* __restrict__ e,
                                              float* __restrict__ E) {
    __shared__ float red[256];
    int t = threadIdx.x;
    float lm = -3.0e38f;
    for (int k = t; k < NN; k += 256) lm = fmaxf(lm, e[k]);
    red[t] = lm; __syncthreads();
    for (int s = 128; s; s >>= 1) { if (t < s) red[t] = fmaxf(red[t], red[t + s]); __syncthreads(); }
    float m = red[0];
    int i = blockIdx.x * 256 + t;
    E[i] = __expf(e[i] - m);
}

// ---------------- Kernel 3: attention row + h_prime ----------------
// One row per block (8192 blocks) — R2 measured that shrinking the grid to
// 2048 blocks x 4 serial rows drops k_att to 2.1 TB/s / 21% occupancy
// (latency-bound).  The 8192-block TLP is what hides the scan->gather chain.
__global__ __launch_bounds__(256) void k_att(const float* __restrict__ edge_adj,
                                             const float* __restrict__ E,
                                             const float* __restrict__ h,
                                             float* __restrict__ att_out,
                                             float* __restrict__ hprime) {
    __shared__ int2 seg[4][WCAP];
    __shared__ vf4  red4[64];
    __shared__ float r4z[4];
    __shared__ int   cnts[4];
    int t = threadIdx.x, w = t >> 6, lane = t & 63;
    int row = blockIdx.x;

    const vf4* rp = (const vf4*)(edge_adj + (size_t)row * NN);
    const vf4* Ep = (const vf4*)E;
    vf4 o[8];
    float zloc = 0.f;
    int cnt = 0;
#pragma unroll
    for (int it = 0; it < 8; ++it) {
        int idx = it * 256 + t;
        vf4 v  = __builtin_nontemporal_load(rp + idx);
        vf4 Ev = Ep[idx];
        int j0 = idx * 4;
        { bool nz = v.x != 0.f; unsigned long long m = __ballot(nz);
          float ox = nz ? Ev.x : 0.f;
          if (nz) seg[w][cnt + mbcnt64(m)] = make_int2(j0,     __float_as_int(v.x * Ev.x));
          cnt += __popcll(m); zloc += ox; o[it].x = ox; }
        { bool nz = v.y != 0.f; unsigned long long m = __ballot(nz);
          float oy = nz ? Ev.y : 0.f;
          if (nz) seg[w][cnt + mbcnt64(m)] = make_int2(j0 + 1, __float_as_int(v.y * Ev.y));
          cnt += __popcll(m); zloc += oy; o[it].y = oy; }
        { bool nz = v.z != 0.f; unsigned long long m = __ballot(nz);
          float oz = nz ? Ev.z : 0.f;
          if (nz) seg[w][cnt + mbcnt64(m)] = make_int2(j0 + 2, __float_as_int(v.z * Ev.z));
          cnt += __popcll(m); zloc += oz; o[it].z = oz; }
        { bool nz = v.w != 0.f; unsigned long long m = __ballot(nz);
          float ow = nz ? Ev.w : 0.f;
          if (nz) seg[w][cnt + mbcnt64(m)] = make_int2(j0 + 3, __float_as_int(v.w * Ev.w));
          cnt += __popcll(m); zloc += ow; o[it].w = ow; }
    }
    if (lane == 0) cnts[w] = cnt;
#pragma unroll
    for (int off = 32; off; off >>= 1) zloc += __shfl_down(zloc, off, 64);
    if (lane == 0) r4z[w] = zloc;
    if (lane < 4) seg[w][cnt + lane] = make_int2(0, 0);   // sentinel pad (v=0)
    __syncthreads();
    float Z = r4z[0] + r4z[1] + r4z[2] + r4z[3];
    int tot = cnts[0] + cnts[1] + cnts[2] + cnts[3];
    float invZ = (tot > 0) ? 1.f / Z : 0.f;

    // ---- h_prime gather: 4x16 lane groups, vf4 loads of h rows ----
    int g = lane >> 4, fl = lane & 15;
    const vf4* Hp = (const vf4*)h;
    vf4 acc = {0.f, 0.f, 0.f, 0.f};
    int cnt4 = (cnt + 3) & ~3;
#pragma unroll 2
    for (int k = 0; k < cnt4; k += 4) {
        int2 sv = seg[w][k + g];           // single ds_read_b64, 16-lane broadcast
        float vv = __int_as_float(sv.y);
        vf4 hv = Hp[(size_t)sv.x * 16 + fl];
        acc.x += vv * hv.x; acc.y += vv * hv.y; acc.z += vv * hv.z; acc.w += vv * hv.w;
    }
    acc.x += __shfl_xor(acc.x, 16, 64); acc.y += __shfl_xor(acc.y, 16, 64);
    acc.z += __shfl_xor(acc.z, 16, 64); acc.w += __shfl_xor(acc.w, 16, 64);
    acc.x += __shfl_xor(acc.x, 32, 64); acc.y += __shfl_xor(acc.y, 32, 64);
    acc.z += __shfl_xor(acc.z, 32, 64); acc.w += __shfl_xor(acc.w, 32, 64);
    if (lane < 16) red4[w * 16 + fl] = acc;   // wave w's 64 features at red[w*64+f]
    __syncthreads();
    const float* red = (const float*)red4;
    if (t < 64)
        hprime[(size_t)row * FF + t] = (red[t] + red[t + 64] + red[t + 128] + red[t + 192]) * invZ;

    // ---- dense coalesced write ----
    vf4* ap = (vf4*)(att_out + (size_t)row * NN);
    float unif = 1.0f / NN;
#pragma unroll
    for (int it = 0; it < 8; ++it) {
        int idx = it * 256 + t;
        vf4 ov = o[it];
        ov.x *= invZ; ov.y *= invZ; ov.z *= invZ; ov.w *= invZ;
        if (tot == 0) { ov.x = unif; ov.y = unif; ov.z = unif; ov.w = unif; }
        __builtin_nontemporal_store(ov, ap + idx);
    }
}

extern "C" void kernel_launch(void* const* d_in, const int* in_sizes, int n_in,
                              void* d_out, int out_size, void* d_ws, size_t ws_size,
                              hipStream_t stream) {
    const float* h        = (const float*)d_in[0];
    const float* node_adj = (const float*)d_in[1];
    const float* edge_adj = (const float*)d_in[2];
    const float* W_att    = (const float*)d_in[3];
    const float* a        = (const float*)d_in[4];

    float* out    = (float*)d_out;
    float* hprime = out;                               // [8192, 64]
    float* att    = out + (size_t)NN * FF;             // [8192, 8192]

    float* e_vec = (float*)d_ws;                       // [8192]
    float* E_vec = e_vec + NN;                         // [8192]

    k_e<<<NN / 4, 256, 0, stream>>>(node_adj, h, W_att, a, e_vec);
    k_prep<<<NN / 256, 256, 0, stream>>>(e_vec, E_vec);
    k_att<<<NN, 256, 0, stream>>>(edge_adj, E_vec, h, att, hprime);
}

// Round 4
// 603.642 us; speedup vs baseline: 1.1371x; 1.0057x over previous
//
#include <hip/hip_runtime.h>
#include <math.h>

#define NN 8192
#define FF 64
#define ALPHA 0.2f
#define ECAP 512   // k_e per-wave nz-list capacity (row mean 164, max ~230, +4 pad)
#define WCAP 256   // k_att per-wave segment capacity (mean 41, max ~90, +4 pad)

typedef float vf4 __attribute__((ext_vector_type(4)));  // clang vector: ok for nontemporal builtins

// popcount of ballot mask below this lane: v_mbcnt_lo + v_mbcnt_hi (2 VALU)
__device__ __forceinline__ unsigned mbcnt64(unsigned long long m) {
    return __builtin_amdgcn_mbcnt_hi((unsigned)(m >> 32),
           __builtin_amdgcn_mbcnt_lo((unsigned)m, 0u));
}

// ---------------- Kernel 1: e[i] ----------------
// Algebraic fusion: (sgn(node_adj) @ (h @ W)) == ((sgn(node_adj) @ h) @ W),
// so gather h rows directly (u = signed sum, 64-dim), then apply W per row:
// a_input = |u @ W|, e = leakyrelu(a_input . a).  k_hatt eliminated.
__global__ __launch_bounds__(256) void k_e(const float* __restrict__ node_adj,
                                           const float* __restrict__ h,
                                           const float* __restrict__ W,
                                           const float* __restrict__ a,
                                           float* __restrict__ e) {
    __shared__ int lists[4][ECAP];
    __shared__ vf4 u_s[4][16];
    int t = threadIdx.x, w = t >> 6, lane = t & 63;
    int row = blockIdx.x * 4 + w;
    const vf4* rp = (const vf4*)(node_adj + (size_t)row * NN);
    int cnt = 0;
#pragma unroll 4
    for (int it = 0; it < 32; ++it) {
        int idx = it * 64 + lane;
        vf4 v = __builtin_nontemporal_load(rp + idx);
        int j0 = idx * 4;
        { bool nz = v.x != 0.f; unsigned long long m = __ballot(nz);
          if (nz) lists[w][cnt + mbcnt64(m)] = (v.x > 0.f) ? (j0 + 1) : -(j0 + 1);
          cnt += __popcll(m); }
        { bool nz = v.y != 0.f; unsigned long long m = __ballot(nz);
          if (nz) lists[w][cnt + mbcnt64(m)] = (v.y > 0.f) ? (j0 + 2) : -(j0 + 2);
          cnt += __popcll(m); }
        { bool nz = v.z != 0.f; unsigned long long m = __ballot(nz);
          if (nz) lists[w][cnt + mbcnt64(m)] = (v.z > 0.f) ? (j0 + 3) : -(j0 + 3);
          cnt += __popcll(m); }
        { bool nz = v.w != 0.f; unsigned long long m = __ballot(nz);
          if (nz) lists[w][cnt + mbcnt64(m)] = (v.w > 0.f) ? (j0 + 4) : -(j0 + 4);
          cnt += __popcll(m); }
    }
    // pad to multiple of 4 with sentinel 0 (contribution forced to 0 below)
    if (lane < 4) lists[w][cnt + lane] = 0;
    // no __syncthreads(): lists/u_s are strictly per-wave; same-wave LDS
    // write->read ordering is handled by in-order DS pipe + lgkmcnt waits.

    int g = lane >> 4, fl = lane & 15;     // group = gathered row, fl = feature quad
    const vf4* Hp = (const vf4*)h;
    vf4 acc = {0.f, 0.f, 0.f, 0.f};
    int cnt4 = (cnt + 3) & ~3;
    // unroll 4: 16 gathered rows in flight; ds_reads are independent so 4
    // dependent ds->vmem->fma chains overlap (latency-bound loop, R3 theory).
#pragma unroll 4
    for (int k = 0; k < cnt4; k += 4) {
        int code = lists[w][k + g];        // 16-lane broadcast, 4 consecutive words
        float s = (code < 0) ? -1.f : (code > 0 ? 1.f : 0.f);
        int aj = (code < 0) ? -code : code;
        int j = (aj > 0) ? aj - 1 : 0;
        vf4 hv = Hp[(size_t)j * 16 + fl];  // 256B contiguous per 16-lane group
        acc.x += s * hv.x; acc.y += s * hv.y; acc.z += s * hv.z; acc.w += s * hv.w;
    }
    // cross-group reduce: groups 0..3 hold partials of the same 64 features
    acc.x += __shfl_xor(acc.x, 16, 64); acc.y += __shfl_xor(acc.y, 16, 64);
    acc.z += __shfl_xor(acc.z, 16, 64); acc.w += __shfl_xor(acc.w, 16, 64);
    acc.x += __shfl_xor(acc.x, 32, 64); acc.y += __shfl_xor(acc.y, 32, 64);
    acc.z += __shfl_xor(acc.z, 32, 64); acc.w += __shfl_xor(acc.w, 32, 64);

    // broadcast u (64 features) to the wave, then apply W: lane = output feature
    if (g == 0) u_s[w][fl] = acc;
    const float* us = (const float*)u_s[w];
    float s = 0.f;
#pragma unroll 8
    for (int k = 0; k < 64; ++k)
        s += us[k] * W[k * 64 + lane];     // us[k]: LDS broadcast; W: coalesced, L1-hot
    float v = fabsf(s) * a[lane];
#pragma unroll
    for (int off = 32; off; off >>= 1) v += __shfl_down(v, off, 64);
    if (lane == 0) e[row] = (v > 0.f) ? v : ALPHA * v;
}

// ---------------- Kernel 2: E[j] = exp(e[j] - max(e)) ----------------
__global__ __launch_bounds__(256) void k_prep(const float* __restrict__ e,
                                              float* __restrict__ E) {
    __shared__ float red[256];
    int t = threadIdx.x;
    float lm = -3.0e38f;
    for (int k = t; k < NN; k += 256) lm = fmaxf(lm, e[k]);
    red[t] = lm; __syncthreads();
    for (int s = 128; s; s >>= 1) { if (t < s) red[t] = fmaxf(red[t], red[t + s]); __syncthreads(); }
    float m = red[0];
    int i = blockIdx.x * 256 + t;
    E[i] = __expf(e[i] - m);
}

// ---------------- Kernel 3: attention row + h_prime ----------------
// One row per block (8192 blocks) — R2 measured that 4 serial rows/block
// drops to 2.1 TB/s / 21% occupancy (latency-bound).  Keep the big grid.
// R4: stage all 16 scan loads in registers BEFORE the ballot chain (the
// chain is pure VALU) -> 16 outstanding VMEM ops/wave instead of ~2-4.
__global__ __launch_bounds__(256) void k_att(const float* __restrict__ edge_adj,
                                             const float* __restrict__ E,
                                             const float* __restrict__ h,
                                             float* __restrict__ att_out,
                                             float* __restrict__ hprime) {
    __shared__ int2 seg[4][WCAP];
    __shared__ vf4  red4[64];
    __shared__ float r4z[4];
    __shared__ int   cnts[4];
    int t = threadIdx.x, w = t >> 6, lane = t & 63;
    int row = blockIdx.x;

    const vf4* rp = (const vf4*)(edge_adj + (size_t)row * NN);
    const vf4* Ep = (const vf4*)E;

    // ---- issue all scan loads up front ----
    vf4 v[8], Ev[8];
#pragma unroll
    for (int it = 0; it < 8; ++it) {
        int idx = it * 256 + t;
        v[it]  = __builtin_nontemporal_load(rp + idx);
        Ev[it] = Ep[idx];
    }

    vf4 o[8];
    float zloc = 0.f;
    int cnt = 0;
#pragma unroll
    for (int it = 0; it < 8; ++it) {
        int j0 = (it * 256 + t) * 4;
        { bool nz = v[it].x != 0.f; unsigned long long m = __ballot(nz);
          float ox = nz ? Ev[it].x : 0.f;
          if (nz) seg[w][cnt + mbcnt64(m)] = make_int2(j0,     __float_as_int(v[it].x * Ev[it].x));
          cnt += __popcll(m); zloc += ox; o[it].x = ox; }
        { bool nz = v[it].y != 0.f; unsigned long long m = __ballot(nz);
          float oy = nz ? Ev[it].y : 0.f;
          if (nz) seg[w][cnt + mbcnt64(m)] = make_int2(j0 + 1, __float_as_int(v[it].y * Ev[it].y));
          cnt += __popcll(m); zloc += oy; o[it].y = oy; }
        { bool nz = v[it].z != 0.f; unsigned long long m = __ballot(nz);
          float oz = nz ? Ev[it].z : 0.f;
          if (nz) seg[w][cnt + mbcnt64(m)] = make_int2(j0 + 2, __float_as_int(v[it].z * Ev[it].z));
          cnt += __popcll(m); zloc += oz; o[it].z = oz; }
        { bool nz = v[it].w != 0.f; unsigned long long m = __ballot(nz);
          float ow = nz ? Ev[it].w : 0.f;
          if (nz) seg[w][cnt + mbcnt64(m)] = make_int2(j0 + 3, __float_as_int(v[it].w * Ev[it].w));
          cnt += __popcll(m); zloc += ow; o[it].w = ow; }
    }
    if (lane == 0) cnts[w] = cnt;
#pragma unroll
    for (int off = 32; off; off >>= 1) zloc += __shfl_down(zloc, off, 64);
    if (lane == 0) r4z[w] = zloc;
    if (lane < 4) seg[w][cnt + lane] = make_int2(0, 0);   // sentinel pad (v=0)
    __syncthreads();
    float Z = r4z[0] + r4z[1] + r4z[2] + r4z[3];
    int tot = cnts[0] + cnts[1] + cnts[2] + cnts[3];
    float invZ = (tot > 0) ? 1.f / Z : 0.f;

    // ---- h_prime gather: 4x16 lane groups, vf4 loads of h rows ----
    int g = lane >> 4, fl = lane & 15;
    const vf4* Hp = (const vf4*)h;
    vf4 acc = {0.f, 0.f, 0.f, 0.f};
    int cnt4 = (cnt + 3) & ~3;
#pragma unroll 4
    for (int k = 0; k < cnt4; k += 4) {
        int2 sv = seg[w][k + g];           // single ds_read_b64, 16-lane broadcast
        float vv = __int_as_float(sv.y);
        vf4 hv = Hp[(size_t)sv.x * 16 + fl];
        acc.x += vv * hv.x; acc.y += vv * hv.y; acc.z += vv * hv.z; acc.w += vv * hv.w;
    }
    acc.x += __shfl_xor(acc.x, 16, 64); acc.y += __shfl_xor(acc.y, 16, 64);
    acc.z += __shfl_xor(acc.z, 16, 64); acc.w += __shfl_xor(acc.w, 16, 64);
    acc.x += __shfl_xor(acc.x, 32, 64); acc.y += __shfl_xor(acc.y, 32, 64);
    acc.z += __shfl_xor(acc.z, 32, 64); acc.w += __shfl_xor(acc.w, 32, 64);
    if (lane < 16) red4[w * 16 + fl] = acc;   // wave w's 64 features at red[w*64+f]
    __syncthreads();
    const float* red = (const float*)red4;
    if (t < 64)
        hprime[(size_t)row * FF + t] = (red[t] + red[t + 64] + red[t + 128] + red[t + 192]) * invZ;

    // ---- dense coalesced write ----
    vf4* ap = (vf4*)(att_out + (size_t)row * NN);
    float unif = 1.0f / NN;
#pragma unroll
    for (int it = 0; it < 8; ++it) {
        int idx = it * 256 + t;
        vf4 ov = o[it];
        ov.x *= invZ; ov.y *= invZ; ov.z *= invZ; ov.w *= invZ;
        if (tot == 0) { ov.x = unif; ov.y = unif; ov.z = unif; ov.w = unif; }
        __builtin_nontemporal_store(ov, ap + idx);
    }
}

extern "C" void kernel_launch(void* const* d_in, const int* in_sizes, int n_in,
                              void* d_out, int out_size, void* d_ws, size_t ws_size,
                              hipStream_t stream) {
    const float* h        = (const float*)d_in[0];
    const float* node_adj = (const float*)d_in[1];
    const float* edge_adj = (const float*)d_in[2];
    const float* W_att    = (const float*)d_in[3];
    const float* a        = (const float*)d_in[4];

    float* out    = (float*)d_out;
    float* hprime = out;                               // [8192, 64]
    float* att    = out + (size_t)NN * FF;             // [8192, 8192]

    float* e_vec = (float*)d_ws;                       // [8192]
    float* E_vec = e_vec + NN;                         // [8192]

    k_e<<<NN / 4, 256, 0, stream>>>(node_adj, h, W_att, a, e_vec);
    k_prep<<<NN / 256, 256, 0, stream>>>(e_vec, E_vec);
    k_att<<<NN, 256, 0, stream>>>(edge_adj, E_vec, h, att, hprime);
}